// Round 10
// baseline (262.046 us; speedup 1.0000x reference)
//
#include <hip/hip_runtime.h>

#define DEV __device__ __forceinline__

typedef __attribute__((ext_vector_type(8)))  short bf16x8;
typedef __attribute__((ext_vector_type(4)))  short s16x4;
typedef __attribute__((ext_vector_type(4)))  float f32x4;
typedef __attribute__((ext_vector_type(16))) float f32x16;
typedef __attribute__((ext_vector_type(4)))  unsigned u32x4;

constexpr int Tt = 1024, TLr = 1022;
constexpr long WSW_BYTES = 704512;   // 43 contiguous 16KB stages

#define MFMA32(a,b,c) __builtin_amdgcn_mfma_f32_32x32x16_bf16((a),(b),(c),0,0,0)

#define GLDS16(gp, lp) __builtin_amdgcn_global_load_lds( \
    (__attribute__((address_space(1))) void*)(void*)(gp), \
    (__attribute__((address_space(3))) void*)(void*)(lp), 16, 0, 0)

// Counted-vmcnt phase boundary (never vmcnt(0) mid-loop).
#define WAITV4() asm volatile("s_waitcnt vmcnt(4)" ::: "memory")
#define WAITV0() asm volatile("s_waitcnt vmcnt(0)" ::: "memory")
#define BARX()   do { __builtin_amdgcn_s_barrier(); \
                      __builtin_amdgcn_sched_barrier(0); } while(0)

DEV short bf16hi(float f){
  unsigned u = __builtin_bit_cast(unsigned, f);
  u += 0x7FFFu + ((u >> 16) & 1u);          // round-to-nearest-even
  return (short)(u >> 16);
}
DEV float bf2f(short h){
  unsigned u = ((unsigned)(unsigned short)h) << 16;
  return __builtin_bit_cast(float, u);
}
DEV void splitbf(float f, short &h, short &l){
  h = bf16hi(f);
  l = bf16hi(f - bf2f(h));
}

DEV unsigned cvtpk(float a, float b){
  unsigned r;
  asm("v_cvt_pk_bf16_f32 %0, %1, %2" : "=v"(r) : "v"(a), "v"(b));
  return r;
}
DEV void plswap(unsigned &a, unsigned &b){
  auto r = __builtin_amdgcn_permlane32_swap((int)a, (int)b, false, false);
  a = (unsigned)r[0]; b = (unsigned)r[1];
}

// ACT: 0 none, 1 tanh, 2 relu, 3 leaky(0.2)
template<int A> DEV float actf(float x){
  if constexpr (A == 1){
    float e = __expf(2.f * x);
    return 1.f - 2.f * __builtin_amdgcn_rcpf(e + 1.f);
  } else if constexpr (A == 2){
    return fmaxf(x, 0.f);
  } else if constexpr (A == 3){
    return x >= 0.f ? x : 0.2f * x;
  }
  return x;
}

// Issue one 16KB stage k -> LDS dst (4 x global_load_lds dwordx4 per thread).
DEV void prefStage(const char* __restrict__ wsW, long k, char* dst, int tid){
  const char* s = wsW + (k << 14);
  #pragma unroll
  for (int it = 0; it < 4; ++it)
    GLDS16(s + it * 4096 + tid * 16, dst + it * 4096 + tid * 16);
}

// C m-tile (16 f32, feats 32m + (r&3)+8(r>>2)+4h) -> next-layer B-fragment
// words, k-groups 2m (regs 0..7) and 2m+1 (regs 8..15).
DEV void packTile(const f32x16& c, unsigned (&Bg0)[4], unsigned (&Bg1)[4]){
  unsigned p0 = cvtpk(c[0], c[1]),  p1 = cvtpk(c[2], c[3]);
  unsigned p2 = cvtpk(c[4], c[5]),  p3 = cvtpk(c[6], c[7]);
  plswap(p0, p2); plswap(p1, p3);
  Bg0[0] = p0; Bg0[1] = p1; Bg0[2] = p2; Bg0[3] = p3;
  p0 = cvtpk(c[8],  c[9]);  p1 = cvtpk(c[10], c[11]);
  p2 = cvtpk(c[12], c[13]); p3 = cvtpk(c[14], c[15]);
  plswap(p0, p2); plswap(p1, p3);
  Bg1[0] = p0; Bg1[1] = p1; Bg1[2] = p2; Bg1[3] = p3;
}

// One m-tile (32 out feats @32*MOUT) over ONE 32-row tile per wave (n=1).
// Stage layout: block (kt*G + GI)*BS, hi@+0 (lo@+1024 if LO). acc init = bias.
// MODE 0: activation + pack to Bout.
// MODE 1: uA[MOUT] -= acc (masked).   MODE 2: uA[MOUT]*=exp(-acc), ldet-=acc.
// MODE 3: store (acc - uA[MOUT]) to resid.
template<int KT,int G,int GI,int MOUT,bool LO,int ACT,int MODE>
DEV void computeMT(const char* __restrict__ Ws, const float* __restrict__ bias,
                   const unsigned (&Bin)[8][4], unsigned (&Bout)[8][4],
                   f32x16 (&uA)[2], float &ldet,
                   float* __restrict__ residBase, int keep, int rowW,
                   int lane, int h4)
{
  constexpr int BS = LO ? 2048 : 1024;
  f32x16 acc;
  #pragma unroll
  for (int q = 0; q < 4; ++q){
    f32x4 bv = *(const f32x4*)(bias + 32 * MOUT + 8 * q + h4);
    #pragma unroll
    for (int j = 0; j < 4; ++j) acc[4 * q + j] = bv[j];
  }
  #pragma unroll
  for (int kt = 0; kt < KT; ++kt){
    const char* wp = Ws + (kt * G + GI) * BS + lane * 16;
    bf16x8 Ah = *(const bf16x8*)wp;
    u32x4 bw = {Bin[kt][0], Bin[kt][1], Bin[kt][2], Bin[kt][3]};
    acc = MFMA32(Ah, __builtin_bit_cast(bf16x8, bw), acc);
    if constexpr (LO){
      bf16x8 Al = *(const bf16x8*)(wp + 1024);
      acc = MFMA32(Al, __builtin_bit_cast(bf16x8, bw), acc);
    }
  }
  if constexpr (MODE == 0){
    #pragma unroll
    for (int i = 0; i < 16; ++i) acc[i] = actf<ACT>(acc[i]);
    packTile(acc, Bout[2 * MOUT], Bout[2 * MOUT + 1]);
  } else if constexpr (MODE == 1){
    #pragma unroll
    for (int r = 0; r < 16; ++r)
      if ((r & 1) != keep) uA[MOUT][r] -= acc[r];
  } else if constexpr (MODE == 2){
    #pragma unroll
    for (int r = 0; r < 16; ++r)
      if ((r & 1) != keep){
        uA[MOUT][r] *= __expf(-acc[r]);
        ldet -= acc[r];
      }
  } else {
    const int col = lane & 31;
    const int tau = rowW + col;
    if (tau < TLr){
      float* rp = residBase + (long)tau * 64 + 32 * MOUT + h4;
      #pragma unroll
      for (int q = 0; q < 4; ++q){
        f32x4 st;
        #pragma unroll
        for (int j = 0; j < 4; ++j)
          st[j] = acc[4 * q + j] - uA[MOUT][4 * q + j];
        *(f32x4*)(rp + 8 * q) = st;
      }
    }
  }
}

// mx = u*mask -> B-fragment words (k-groups 0..3, K=64).
DEV void buildMaskedB(const f32x16 (&u)[2], unsigned (&B)[8][4], int keep){
  const float mOdd  = (keep == 1) ? 1.f : 0.f;
  const float mEven = 1.f - mOdd;
  #pragma unroll
  for (int mi = 0; mi < 2; ++mi){
    f32x16 v;
    #pragma unroll
    for (int r = 0; r < 16; ++r)
      v[r] = u[mi][r] * ((r & 1) ? mOdd : mEven);
    packTile(v, B[2 * mi], B[2 * mi + 1]);
  }
}

// f1 window input straight from global x into B-fragment words (128 k-feats).
DEV void buildWin(unsigned (&B)[8][4], const float* __restrict__ xb,
                  int rowW, int lane){
  const int col = lane & 31, h = lane >> 5;
  const int tau = rowW + col;
  #pragma unroll
  for (int g = 0; g < 8; ++g){
    int xr = tau + (g >= 4 ? 1 : 0);
    if (xr > Tt - 1) xr = Tt - 1;
    const int fo = (16 * g + 8 * h) & 63;
    const float* p = xb + xr * 64 + fo;
    f32x4 a = *(const f32x4*)p, b = *(const f32x4*)(p + 4);
    B[g][0] = cvtpk(a[0], a[1]); B[g][1] = cvtpk(a[2], a[3]);
    B[g][2] = cvtpk(b[0], b[1]); B[g][3] = cvtpk(b[2], b[3]);
  }
}

// ---- Weight preconversion -> 43 contiguous 16KB stages, fragment-linear ----
// Per flow blk b @ b*196608 (t single-bf16, s hi/lo):
//   t0@+0(16K,G4) t1@+16384(2x16K,G2) t2@+49152(16K,G2)
//   s0@+65536(2x16K,G2) s1@+98304(4x16K,G1) s2@+163840(2x16K,G1)
// f1 (single): h_i@589824+i*32768 (2x16K,G2), o@688128(16K,G2). Tot 704512.
__global__ void pnl_conv(const float* __restrict__ sW0, const float* __restrict__ sW1,
                         const float* __restrict__ sW2, const float* __restrict__ tW0,
                         const float* __restrict__ tW1, const float* __restrict__ tW2,
                         const float* __restrict__ f1_hW, const float* __restrict__ f1_oW,
                         char* __restrict__ wsW)
{
  const int cid = blockIdx.x * 256 + threadIdx.x;    // 0..31743
  const float* src; long base; int hs, unit, BS, lg; bool LO;
  if (cid < 24576){
    const int blk = cid >> 13, r = cid & 8191;
    const long bb = (long)blk * 196608;
    if      (r < 1024){ src = tW0 + blk*8192;  hs=6; base=bb;        BS=1024; lg=2; LO=false; unit=r; }
    else if (r < 3072){ src = tW1 + blk*16384; hs=7; base=bb+16384;  BS=1024; lg=1; LO=false; unit=r-1024; }
    else if (r < 4096){ src = tW2 + blk*8192;  hs=7; base=bb+49152;  BS=1024; lg=1; LO=false; unit=r-3072; }
    else if (r < 5120){ src = sW0 + blk*8192;  hs=6; base=bb+65536;  BS=2048; lg=1; LO=true;  unit=r-4096; }
    else if (r < 7168){ src = sW1 + blk*16384; hs=7; base=bb+98304;  BS=2048; lg=0; LO=true;  unit=r-5120; }
    else              { src = sW2 + blk*8192;  hs=7; base=bb+163840; BS=2048; lg=0; LO=true;  unit=r-7168; }
  } else {
    const int r = cid - 24576;
    if (r < 6144){ const int l = r >> 11; src = f1_hW + l*16384; hs=7; base=589824+(long)l*32768; BS=1024; lg=1; LO=false; unit=r&2047; }
    else         { src = f1_oW; hs=7; base=688128; BS=1024; lg=1; LO=false; unit=r-6144; }
  }
  const int e    = unit << 3;
  const int feat = e >> hs;
  const int k    = e & ((1 << hs) - 1);
  const int m    = feat >> 5;
  const int stage = m >> lg;
  const int gi    = m & ((1 << lg) - 1);
  const int lane  = (feat & 31) | (((k >> 3) & 1) << 5);
  const long off  = base + (long)stage * 16384
                  + (long)((((k >> 4) << lg) + gi) * BS) + lane * 16;
  const float* sp = src + ((long)feat << hs) + k;
  f32x4 v0 = *(const f32x4*)sp, v1 = *(const f32x4*)(sp + 4);
  s16x4 ha, hb, la, lb;
  #pragma unroll
  for (int j = 0; j < 4; ++j){
    short hh, ll;
    splitbf(v0[j], hh, ll); ha[j] = hh; la[j] = ll;
    splitbf(v1[j], hh, ll); hb[j] = hh; lb[j] = ll;
  }
  *(s16x4*)(wsW + off)     = ha;
  *(s16x4*)(wsW + off + 8) = hb;
  if (LO){
    *(s16x4*)(wsW + off + 1024)     = la;
    *(s16x4*)(wsW + off + 1024 + 8) = lb;
  }
}

#define CMT(KT,G,GI,MOUT,LO,ACT,MODE,WS,BIAS,BIN,BOUT) \
  computeMT<KT,G,GI,MOUT,LO,ACT,MODE>(WS,BIAS,BIN,BOUT,uA,ldet,residBase,keep,rowW,lane,h4)

__global__ __launch_bounds__(256, 3)
void pnl_main(const float* __restrict__ x,
              const float* __restrict__ f1_hb, const float* __restrict__ f1_ob,
              const float* __restrict__ sb0, const float* __restrict__ sb1,
              const float* __restrict__ sb2, const float* __restrict__ tb0,
              const float* __restrict__ tb1, const float* __restrict__ tb2,
              const char* __restrict__ wsW,
              float* __restrict__ resid, float* __restrict__ wsPart)
{
  __shared__ __align__(16) char Wb[49152];      // 3 x 16KB slots -> 3 wg/CU
  char* const W0 = Wb;
  char* const W1 = Wb + 16384;
  char* const W2 = Wb + 32768;

  const int tid  = threadIdx.x, w = tid >> 6, lane = tid & 63;
  const int col  = lane & 31, h4 = (lane >> 5) * 4;
  const int bIdx = blockIdx.x >> 3;
  const int t0w  = (blockIdx.x & 7) << 7;       // 8 tiles of 128 rows
  const int rowW = t0w + w * 32;                // wave's first row (t index)
  const float* xb = x + (long)bIdx * Tt * 64;
  float* __restrict__ residBase = resid + (long)bIdx * TLr * 64;

  // u init FIRST (so its vmcnt wait doesn't drain the prefetch pipeline)
  f32x16 uA[2];
  #pragma unroll
  for (int mi = 0; mi < 2; ++mi){
    int xr = rowW + col + 2; if (xr > Tt - 1) xr = Tt - 1;
    #pragma unroll
    for (int q = 0; q < 4; ++q){
      f32x4 v = *(const f32x4*)(xb + xr * 64 + 32 * mi + 8 * q + h4);
      #pragma unroll
      for (int j = 0; j < 4; ++j) uA[mi][4 * q + j] = v[j];
    }
  }
  __builtin_amdgcn_sched_barrier(0);            // keep uA loads older than prefs

  prefStage(wsW, 0, W0, tid);                   // stage 0 (blk0 t0)
  prefStage(wsW, 1, W1, tid);                   // stage 1 (blk0 t1h0)

  float ldet = 0.f;
  unsigned Bx[8][4], By[8][4];

  buildMaskedB(uA, Bx, 1);                      // blk0 keeps odd feats

  #pragma unroll 1
  for (int blk = 0; blk < 3; ++blk){
    const long kb = (long)blk * 12;
    const int keep = 1 - (blk & 1);
    const float* tb0b = tb0 + blk * 128; const float* tb1b = tb1 + blk * 128;
    const float* tb2b = tb2 + blk * 64;
    const float* sb0b = sb0 + blk * 128; const float* sb1b = sb1 + blk * 128;
    const float* sb2b = sb2 + blk * 64;

    // p0 t0 [W0]: Bx(mx)->By, relu
    WAITV4(); BARX(); prefStage(wsW, kb + 2, W2, tid);
    CMT(4,4,0,0,false,2,0, W0, tb0b, Bx, By);
    CMT(4,4,1,1,false,2,0, W0, tb0b, Bx, By);
    CMT(4,4,2,2,false,2,0, W0, tb0b, Bx, By);
    CMT(4,4,3,3,false,2,0, W0, tb0b, Bx, By);
    // p1 t1h0 [W1]: By->Bx(m0,m1)
    WAITV4(); BARX(); prefStage(wsW, kb + 3, W0, tid);
    CMT(8,2,0,0,false,2,0, W1, tb1b, By, Bx);
    CMT(8,2,1,1,false,2,0, W1, tb1b, By, Bx);
    // p2 t1h1 [W2]: By->Bx(m2,m3)
    WAITV4(); BARX(); prefStage(wsW, kb + 4, W1, tid);
    CMT(8,2,0,2,false,2,0, W2, tb1b, By, Bx);
    CMT(8,2,1,3,false,2,0, W2, tb1b, By, Bx);
    // p3 t2 [W0]: Bx -> (uA -= t, masked); rebuild mx -> By
    WAITV4(); BARX(); prefStage(wsW, kb + 5, W2, tid);
    CMT(8,2,0,0,false,0,1, W0, tb2b, Bx, By);
    CMT(8,2,1,1,false,0,1, W0, tb2b, Bx, By);
    buildMaskedB(uA, By, keep);
    // p4 s0h0 [W1]: By(mx)->Bx(m0,m1), tanh, hi/lo
    WAITV4(); BARX(); prefStage(wsW, kb + 6, W0, tid);
    CMT(4,2,0,0,true,1,0, W1, sb0b, By, Bx);
    CMT(4,2,1,1,true,1,0, W1, sb0b, By, Bx);
    // p5 s0h1 [W2]: By->Bx(m2,m3)
    WAITV4(); BARX(); prefStage(wsW, kb + 7, W1, tid);
    CMT(4,2,0,2,true,1,0, W2, sb0b, By, Bx);
    CMT(4,2,1,3,true,1,0, W2, sb0b, By, Bx);
    // p6-p9 s1 quarters: Bx->By
    WAITV4(); BARX(); prefStage(wsW, kb + 8, W2, tid);
    CMT(8,1,0,0,true,1,0, W0, sb1b, Bx, By);
    WAITV4(); BARX(); prefStage(wsW, kb + 9, W0, tid);
    CMT(8,1,0,1,true,1,0, W1, sb1b, Bx, By);
    WAITV4(); BARX(); prefStage(wsW, kb + 10, W1, tid);
    CMT(8,1,0,2,true,1,0, W2, sb1b, Bx, By);
    WAITV4(); BARX(); prefStage(wsW, kb + 11, W2, tid);
    CMT(8,1,0,3,true,1,0, W0, sb1b, Bx, By);
    // p10 s2h0 [W1]: By -> (uA m0: *=exp(-s), ldet)
    WAITV4(); BARX(); prefStage(wsW, kb + 12, W0, tid);
    CMT(8,1,0,0,true,0,2, W1, sb2b, By, Bx);
    // p11 s2h1 [W2]: By -> (uA m1); next input
    WAITV4(); BARX(); prefStage(wsW, kb + 13, W1, tid);
    CMT(8,1,0,1,true,0,2, W2, sb2b, By, Bx);
    if (blk < 2) buildMaskedB(uA, Bx, 1 - ((blk + 1) & 1));
    else         buildWin(Bx, xb, rowW, lane);   // one-time vmcnt drain, accepted
  }

  // ---- f1 (single-bf16), leaky(0.2); stages 36..42 ----
  {
    const int keep = 0;                          // unused by MODE 0/3
    // 36 h0a [W0]
    WAITV4(); BARX(); prefStage(wsW, 38, W2, tid);
    CMT(8,2,0,0,false,3,0, W0, f1_hb, Bx, By);
    CMT(8,2,1,1,false,3,0, W0, f1_hb, Bx, By);
    // 37 h0b [W1]
    WAITV4(); BARX(); prefStage(wsW, 39, W0, tid);
    CMT(8,2,0,2,false,3,0, W1, f1_hb, Bx, By);
    CMT(8,2,1,3,false,3,0, W1, f1_hb, Bx, By);
    // 38 h1a [W2]
    WAITV4(); BARX(); prefStage(wsW, 40, W1, tid);
    CMT(8,2,0,0,false,3,0, W2, f1_hb + 128, By, Bx);
    CMT(8,2,1,1,false,3,0, W2, f1_hb + 128, By, Bx);
    // 39 h1b [W0]
    WAITV4(); BARX(); prefStage(wsW, 41, W2, tid);
    CMT(8,2,0,2,false,3,0, W0, f1_hb + 128, By, Bx);
    CMT(8,2,1,3,false,3,0, W0, f1_hb + 128, By, Bx);
    // 40 h2a [W1]
    WAITV4(); BARX(); prefStage(wsW, 42, W0, tid);
    CMT(8,2,0,0,false,3,0, W1, f1_hb + 256, Bx, By);
    CMT(8,2,1,1,false,3,0, W1, f1_hb + 256, Bx, By);
    // 41 h2b [W2] (no more prefetch; stage 42 still in flight)
    WAITV4(); BARX();
    CMT(8,2,0,2,false,3,0, W2, f1_hb + 256, Bx, By);
    CMT(8,2,1,3,false,3,0, W2, f1_hb + 256, Bx, By);
    // 42 o [W0]: By -> resid (acc - uA), direct global store
    WAITV0(); BARX();
    CMT(8,2,0,0,false,0,3, W0, f1_ob, By, Bx);
    CMT(8,2,1,1,false,0,3, W0, f1_ob, By, Bx);
  }

  // logdet: row tau's sum is split across lane pair (col, col+32);
  // 64-lane butterfly sums all 32 rows of this wave exactly once.
  const int tau = rowW + col;
  float s = (tau < TLr) ? ldet : 0.f;
  #pragma unroll
  for (int off = 1; off < 64; off <<= 1) s += __shfl_xor(s, off);
  if (lane == 0) wsPart[blockIdx.x * 4 + w] = s;
}

// Deterministic final reduce: 8 tiles x 4 waves per batch element.
__global__ void pnl_ldet(const float* __restrict__ ws, float* __restrict__ outLd){
  const int b = threadIdx.x;
  float s = 0.f;
  #pragma unroll
  for (int t = 0; t < 32; ++t) s += ws[b * 32 + t];
  outLd[b] = s;
}

extern "C" void kernel_launch(void* const* d_in, const int* in_sizes, int n_in,
                              void* d_out, int out_size, void* d_ws, size_t ws_size,
                              hipStream_t stream){
  const float* x     = (const float*)d_in[0];
  const float* f1_hW = (const float*)d_in[1];
  const float* f1_hb = (const float*)d_in[2];
  const float* f1_oW = (const float*)d_in[3];
  const float* f1_ob = (const float*)d_in[4];
  const float* sW0   = (const float*)d_in[5];
  const float* sb0   = (const float*)d_in[6];
  const float* sW1   = (const float*)d_in[7];
  const float* sb1   = (const float*)d_in[8];
  const float* sW2   = (const float*)d_in[9];
  const float* sb2   = (const float*)d_in[10];
  const float* tW0   = (const float*)d_in[11];
  const float* tb0   = (const float*)d_in[12];
  const float* tW1   = (const float*)d_in[13];
  const float* tb1   = (const float*)d_in[14];
  const float* tW2   = (const float*)d_in[15];
  const float* tb2   = (const float*)d_in[16];

  char*  wsW    = (char*)d_ws;
  float* wsPart = (float*)(wsW + WSW_BYTES);          // 2048*4 floats
  float* resid  = (float*)d_out;
  float* outLd  = resid + (long)256 * TLr * 64;

  pnl_conv<<<dim3(124), dim3(256), 0, stream>>>(sW0, sW1, sW2, tW0, tW1, tW2,
                                                f1_hW, f1_oW, wsW);
  pnl_main<<<dim3(2048), dim3(256), 0, stream>>>(
      x, f1_hb, f1_ob, sb0, sb1, sb2, tb0, tb1, tb2, wsW, resid, wsPart);
  pnl_ldet<<<dim3(1), dim3(256), 0, stream>>>(wsPart, outLd);
}

// Round 11
// 199.553 us; speedup vs baseline: 1.3132x; 1.3132x over previous
//
#include <hip/hip_runtime.h>

#define DEV __device__ __forceinline__

typedef __attribute__((ext_vector_type(8)))  short bf16x8;
typedef __attribute__((ext_vector_type(4)))  short s16x4;
typedef __attribute__((ext_vector_type(4)))  float f32x4;
typedef __attribute__((ext_vector_type(16))) float f32x16;
typedef __attribute__((ext_vector_type(4)))  unsigned u32x4;

constexpr int Tt = 1024, TLr = 1022;
constexpr long WSW_BYTES = 557056;   // 34 contiguous 16KB stages

#define MFMA32(a,b,c) __builtin_amdgcn_mfma_f32_32x32x16_bf16((a),(b),(c),0,0,0)

#define GLDS16(gp, lp) __builtin_amdgcn_global_load_lds( \
    (__attribute__((address_space(1))) void*)(void*)(gp), \
    (__attribute__((address_space(3))) void*)(void*)(lp), 16, 0, 0)

DEV short bf16hi(float f){
  unsigned u = __builtin_bit_cast(unsigned, f);
  u += 0x7FFFu + ((u >> 16) & 1u);          // round-to-nearest-even
  return (short)(u >> 16);
}
DEV float bf2f(short h){
  unsigned u = ((unsigned)(unsigned short)h) << 16;
  return __builtin_bit_cast(float, u);
}
DEV void splitbf(float f, short &h, short &l){
  h = bf16hi(f);
  l = bf16hi(f - bf2f(h));
}

DEV unsigned cvtpk(float a, float b){
  unsigned r;
  asm("v_cvt_pk_bf16_f32 %0, %1, %2" : "=v"(r) : "v"(a), "v"(b));
  return r;
}
DEV void plswap(unsigned &a, unsigned &b){
  auto r = __builtin_amdgcn_permlane32_swap((int)a, (int)b, false, false);
  a = (unsigned)r[0]; b = (unsigned)r[1];
}

// ACT: 0 none, 1 tanh, 2 relu, 3 leaky(0.2)
template<int A> DEV float actf(float x){
  if constexpr (A == 1){
    float e = __expf(2.f * x);
    return 1.f - 2.f * __builtin_amdgcn_rcpf(e + 1.f);
  } else if constexpr (A == 2){
    return fmaxf(x, 0.f);
  } else if constexpr (A == 3){
    return x >= 0.f ? x : 0.2f * x;
  }
  return x;
}

// Issue one 16KB stage k -> LDS dst (4 x global_load_lds dwordx4 per thread).
DEV void prefStage(const char* __restrict__ wsW, long k, char* dst, int tid){
  const char* s = wsW + (k << 14);
  #pragma unroll
  for (int it = 0; it < 4; ++it)
    GLDS16(s + it * 4096 + tid * 16, dst + it * 4096 + tid * 16);
}

// C m-tile (16 f32, feats 32m + (r&3)+8(r>>2)+4h) -> next-layer B-fragment
// words, k-groups 2m (regs 0..7) and 2m+1 (regs 8..15).
DEV void packTile(const f32x16& c, unsigned (&Bg0)[4], unsigned (&Bg1)[4]){
  unsigned p0 = cvtpk(c[0], c[1]),  p1 = cvtpk(c[2], c[3]);
  unsigned p2 = cvtpk(c[4], c[5]),  p3 = cvtpk(c[6], c[7]);
  plswap(p0, p2); plswap(p1, p3);
  Bg0[0] = p0; Bg0[1] = p1; Bg0[2] = p2; Bg0[3] = p3;
  p0 = cvtpk(c[8],  c[9]);  p1 = cvtpk(c[10], c[11]);
  p2 = cvtpk(c[12], c[13]); p3 = cvtpk(c[14], c[15]);
  plswap(p0, p2); plswap(p1, p3);
  Bg1[0] = p0; Bg1[1] = p1; Bg1[2] = p2; Bg1[3] = p3;
}

// One m-tile (32 out feats @32*MOUT) over n=2 row-tiles (64 rows/wave).
// Stage layout: block (kt*G + GI)*BS, hi@+0 (lo@+1024 if LO). acc init = bias.
// MODE 0: activation + pack to Bout.
// MODE 1: uA[MOUT] -= acc (masked).   MODE 2: uA[MOUT]*=exp(-acc), ldet-=acc.
// MODE 3: store (acc - uA[MOUT]) to resid.
template<int KT,int G,int GI,int MOUT,bool LO,int ACT,int MODE>
DEV void computeMT(const char* __restrict__ Ws, const float* __restrict__ bias,
                   const unsigned (&Bin)[2][8][4], unsigned (&Bout)[2][8][4],
                   f32x16 (&uA)[2][2], float (&ldet)[2],
                   float* __restrict__ residBase, int keep, int rowW,
                   int lane, int h4)
{
  constexpr int BS = LO ? 2048 : 1024;
  f32x16 acc[2];
  #pragma unroll
  for (int q = 0; q < 4; ++q){
    f32x4 bv = *(const f32x4*)(bias + 32 * MOUT + 8 * q + h4);
    #pragma unroll
    for (int j = 0; j < 4; ++j){ acc[0][4*q+j] = bv[j]; acc[1][4*q+j] = bv[j]; }
  }
  __builtin_amdgcn_s_setprio(1);
  #pragma unroll
  for (int kt = 0; kt < KT; ++kt){
    const char* wp = Ws + (kt * G + GI) * BS + lane * 16;
    bf16x8 Ah = *(const bf16x8*)wp;
    #pragma unroll
    for (int n = 0; n < 2; ++n){
      u32x4 bw = {Bin[n][kt][0], Bin[n][kt][1], Bin[n][kt][2], Bin[n][kt][3]};
      acc[n] = MFMA32(Ah, __builtin_bit_cast(bf16x8, bw), acc[n]);
    }
    if constexpr (LO){
      bf16x8 Al = *(const bf16x8*)(wp + 1024);
      #pragma unroll
      for (int n = 0; n < 2; ++n){
        u32x4 bw = {Bin[n][kt][0], Bin[n][kt][1], Bin[n][kt][2], Bin[n][kt][3]};
        acc[n] = MFMA32(Al, __builtin_bit_cast(bf16x8, bw), acc[n]);
      }
    }
  }
  __builtin_amdgcn_s_setprio(0);
  if constexpr (MODE == 0){
    #pragma unroll
    for (int n = 0; n < 2; ++n){
      #pragma unroll
      for (int i = 0; i < 16; ++i) acc[n][i] = actf<ACT>(acc[n][i]);
      packTile(acc[n], Bout[n][2 * MOUT], Bout[n][2 * MOUT + 1]);
    }
  } else if constexpr (MODE == 1){
    #pragma unroll
    for (int n = 0; n < 2; ++n)
      #pragma unroll
      for (int r = 0; r < 16; ++r)
        if ((r & 1) != keep) uA[MOUT][n][r] -= acc[n][r];
  } else if constexpr (MODE == 2){
    #pragma unroll
    for (int n = 0; n < 2; ++n)
      #pragma unroll
      for (int r = 0; r < 16; ++r)
        if ((r & 1) != keep){
          uA[MOUT][n][r] *= __expf(-acc[n][r]);
          ldet[n] -= acc[n][r];
        }
  } else {
    const int col = lane & 31;
    #pragma unroll
    for (int n = 0; n < 2; ++n){
      const int tau = rowW + n * 32 + col;
      if (tau < TLr){
        float* rp = residBase + (long)tau * 64 + 32 * MOUT + h4;
        #pragma unroll
        for (int q = 0; q < 4; ++q){
          f32x4 st;
          #pragma unroll
          for (int j = 0; j < 4; ++j)
            st[j] = acc[n][4 * q + j] - uA[MOUT][n][4 * q + j];
          *(f32x4*)(rp + 8 * q) = st;
        }
      }
    }
  }
}

// mx = u*mask -> B-fragment words (k-groups 0..3, K=64), both n.
DEV void buildMaskedB(const f32x16 (&u)[2][2], unsigned (&B)[2][8][4], int keep){
  const float mOdd  = (keep == 1) ? 1.f : 0.f;
  const float mEven = 1.f - mOdd;
  #pragma unroll
  for (int n = 0; n < 2; ++n)
    #pragma unroll
    for (int mi = 0; mi < 2; ++mi){
      f32x16 v;
      #pragma unroll
      for (int r = 0; r < 16; ++r)
        v[r] = u[mi][n][r] * ((r & 1) ? mOdd : mEven);
      packTile(v, B[n][2 * mi], B[n][2 * mi + 1]);
    }
}

// f1 window input straight from global x into B-fragment words (128 k-feats).
DEV void buildWin(unsigned (&B)[2][8][4], const float* __restrict__ xb,
                  int rowW, int lane){
  const int col = lane & 31, h = lane >> 5;
  #pragma unroll
  for (int n = 0; n < 2; ++n){
    const int tau = rowW + n * 32 + col;
    #pragma unroll
    for (int g = 0; g < 8; ++g){
      int xr = tau + (g >= 4 ? 1 : 0);
      if (xr > Tt - 1) xr = Tt - 1;
      const int fo = (16 * g + 8 * h) & 63;
      const float* p = xb + xr * 64 + fo;
      f32x4 a = *(const f32x4*)p, b = *(const f32x4*)(p + 4);
      B[n][g][0] = cvtpk(a[0], a[1]); B[n][g][1] = cvtpk(a[2], a[3]);
      B[n][g][2] = cvtpk(b[0], b[1]); B[n][g][3] = cvtpk(b[2], b[3]);
    }
  }
}

// ---- Weight preconversion -> 34 contiguous 16KB stages, fragment-linear ----
// Per flow blk b @ b*147456 (t,s0,s1 single-bf16; s2 hi/lo dual):
//   t0@+0(1st,G4) t1@+16384(2st,G2) t2@+49152(1st,G2)
//   s0@+65536(1st,G4) s1@+81920(2st,G2) s2@+114688(2st,G1,dual)
// f1 (single): h_i@442368+i*32768 (2st,G2), o@540672(1st,G2). Tot 557056.
__global__ void pnl_conv(const float* __restrict__ sW0, const float* __restrict__ sW1,
                         const float* __restrict__ sW2, const float* __restrict__ tW0,
                         const float* __restrict__ tW1, const float* __restrict__ tW2,
                         const float* __restrict__ f1_hW, const float* __restrict__ f1_oW,
                         char* __restrict__ wsW)
{
  const int cid = blockIdx.x * 256 + threadIdx.x;    // 0..31743
  const float* src; long base; int hs, unit, BS, lg; bool LO;
  if (cid < 24576){
    const int blk = cid >> 13, r = cid & 8191;
    const long bb = (long)blk * 147456;
    if      (r < 1024){ src = tW0 + blk*8192;  hs=6; base=bb;        BS=1024; lg=2; LO=false; unit=r; }
    else if (r < 3072){ src = tW1 + blk*16384; hs=7; base=bb+16384;  BS=1024; lg=1; LO=false; unit=r-1024; }
    else if (r < 4096){ src = tW2 + blk*8192;  hs=7; base=bb+49152;  BS=1024; lg=1; LO=false; unit=r-3072; }
    else if (r < 5120){ src = sW0 + blk*8192;  hs=6; base=bb+65536;  BS=1024; lg=2; LO=false; unit=r-4096; }
    else if (r < 7168){ src = sW1 + blk*16384; hs=7; base=bb+81920;  BS=1024; lg=1; LO=false; unit=r-5120; }
    else              { src = sW2 + blk*8192;  hs=7; base=bb+114688; BS=2048; lg=0; LO=true;  unit=r-7168; }
  } else {
    const int r = cid - 24576;
    if (r < 6144){ const int l = r >> 11; src = f1_hW + l*16384; hs=7; base=442368+(long)l*32768; BS=1024; lg=1; LO=false; unit=r&2047; }
    else         { src = f1_oW; hs=7; base=540672; BS=1024; lg=1; LO=false; unit=r-6144; }
  }
  const int e    = unit << 3;
  const int feat = e >> hs;
  const int k    = e & ((1 << hs) - 1);
  const int m    = feat >> 5;
  const int stage = m >> lg;
  const int gi    = m & ((1 << lg) - 1);
  const int lane  = (feat & 31) | (((k >> 3) & 1) << 5);
  const long off  = base + (long)stage * 16384
                  + (long)((((k >> 4) << lg) + gi) * BS) + lane * 16;
  const float* sp = src + ((long)feat << hs) + k;
  f32x4 v0 = *(const f32x4*)sp, v1 = *(const f32x4*)(sp + 4);
  s16x4 ha, hb, la, lb;
  #pragma unroll
  for (int j = 0; j < 4; ++j){
    short hh, ll;
    splitbf(v0[j], hh, ll); ha[j] = hh; la[j] = ll;
    splitbf(v1[j], hh, ll); hb[j] = hh; lb[j] = ll;
  }
  *(s16x4*)(wsW + off)     = ha;
  *(s16x4*)(wsW + off + 8) = hb;
  if (LO){
    *(s16x4*)(wsW + off + 1024)     = la;
    *(s16x4*)(wsW + off + 1024 + 8) = lb;
  }
}

#define CMT(KT,G,GI,MOUT,LO,ACT,MODE,WS,BIAS,BIN,BOUT) \
  computeMT<KT,G,GI,MOUT,LO,ACT,MODE>(WS,BIAS,BIN,BOUT,uA,ldet,residBase,keep,rowW,lane,h4)

__global__ __launch_bounds__(256, 2)
void pnl_main(const float* __restrict__ x,
              const float* __restrict__ f1_hb, const float* __restrict__ f1_ob,
              const float* __restrict__ sb0, const float* __restrict__ sb1,
              const float* __restrict__ sb2, const float* __restrict__ tb0,
              const float* __restrict__ tb1, const float* __restrict__ tb2,
              const char* __restrict__ wsW,
              float* __restrict__ resid, float* __restrict__ wsPart)
{
  __shared__ __align__(16) char Wb[2][16384];   // 32 KB -> 2 independent wg/CU

  const int tid  = threadIdx.x, w = tid >> 6, lane = tid & 63;
  const int col  = lane & 31, h4 = (lane >> 5) * 4;
  const int bIdx = blockIdx.x >> 2;
  const int t0w  = (blockIdx.x & 3) << 8;       // 4 tiles of 256 rows
  const int rowW = t0w + w * 64;                // wave's first row (t index)
  const float* xb = x + (long)bIdx * Tt * 64;
  float* __restrict__ residBase = resid + (long)bIdx * TLr * 64;

  prefStage(wsW, 0, Wb[0], tid);                // stage 0 (blk0 t0)

  // u init = x[b, tau+2, :] in C-fragment layout (64 rows/wave, n=2)
  f32x16 uA[2][2];
  #pragma unroll
  for (int mi = 0; mi < 2; ++mi)
    #pragma unroll
    for (int n = 0; n < 2; ++n){
      int xr = rowW + n * 32 + col + 2; if (xr > Tt - 1) xr = Tt - 1;
      #pragma unroll
      for (int q = 0; q < 4; ++q){
        f32x4 v = *(const f32x4*)(xb + xr * 64 + 32 * mi + 8 * q + h4);
        #pragma unroll
        for (int j = 0; j < 4; ++j) uA[mi][n][4 * q + j] = v[j];
      }
    }

  float ldet[2] = {0.f, 0.f};
  unsigned Bx[2][8][4], By[2][8][4];

  buildMaskedB(uA, Bx, 1);                      // blk0 keeps odd feats
  __syncthreads();

  #pragma unroll 1
  for (int blk = 0; blk < 3; ++blk){
    const int kb = blk * 9;
    const int par = kb & 1;
    char* const WA = Wb[par];                   // even-j phases
    char* const WB = Wb[par ^ 1];               // odd-j phases
    const int keep = 1 - (blk & 1);
    const float* tb0b = tb0 + blk * 128; const float* tb1b = tb1 + blk * 128;
    const float* tb2b = tb2 + blk * 64;
    const float* sb0b = sb0 + blk * 128; const float* sb1b = sb1 + blk * 128;
    const float* sb2b = sb2 + blk * 64;

    // p0 t0 [WA]: Bx(mx)->By, relu
    prefStage(wsW, kb + 1, WB, tid);
    CMT(4,4,0,0,false,2,0, WA, tb0b, Bx, By);
    CMT(4,4,1,1,false,2,0, WA, tb0b, Bx, By);
    CMT(4,4,2,2,false,2,0, WA, tb0b, Bx, By);
    CMT(4,4,3,3,false,2,0, WA, tb0b, Bx, By);
    __syncthreads();
    // p1 t1h0 [WB]: By->Bx(m0,m1)
    prefStage(wsW, kb + 2, WA, tid);
    CMT(8,2,0,0,false,2,0, WB, tb1b, By, Bx);
    CMT(8,2,1,1,false,2,0, WB, tb1b, By, Bx);
    __syncthreads();
    // p2 t1h1 [WA]: By->Bx(m2,m3)
    prefStage(wsW, kb + 3, WB, tid);
    CMT(8,2,0,2,false,2,0, WA, tb1b, By, Bx);
    CMT(8,2,1,3,false,2,0, WA, tb1b, By, Bx);
    __syncthreads();
    // p3 t2 [WB]: Bx -> (uA -= t, masked); rebuild mx -> By
    prefStage(wsW, kb + 4, WA, tid);
    CMT(8,2,0,0,false,0,1, WB, tb2b, Bx, By);
    CMT(8,2,1,1,false,0,1, WB, tb2b, Bx, By);
    buildMaskedB(uA, By, keep);
    __syncthreads();
    // p4 s0 [WA]: By(mx)->Bx, tanh (single-bf16)
    prefStage(wsW, kb + 5, WB, tid);
    CMT(4,4,0,0,false,1,0, WA, sb0b, By, Bx);
    CMT(4,4,1,1,false,1,0, WA, sb0b, By, Bx);
    CMT(4,4,2,2,false,1,0, WA, sb0b, By, Bx);
    CMT(4,4,3,3,false,1,0, WA, sb0b, By, Bx);
    __syncthreads();
    // p5 s1h0 [WB]: Bx->By(m0,m1), tanh (single-bf16)
    prefStage(wsW, kb + 6, WA, tid);
    CMT(8,2,0,0,false,1,0, WB, sb1b, Bx, By);
    CMT(8,2,1,1,false,1,0, WB, sb1b, Bx, By);
    __syncthreads();
    // p6 s1h1 [WA]: Bx->By(m2,m3)
    prefStage(wsW, kb + 7, WB, tid);
    CMT(8,2,0,2,false,1,0, WA, sb1b, Bx, By);
    CMT(8,2,1,3,false,1,0, WA, sb1b, Bx, By);
    __syncthreads();
    // p7 s2h0 [WB]: By -> (uA m0: *=exp(-s), ldet)  [hi/lo dual]
    prefStage(wsW, kb + 8, WA, tid);
    CMT(8,1,0,0,true,0,2, WB, sb2b, By, Bx);
    __syncthreads();
    // p8 s2h1 [WA]: By -> (uA m1); next input -> Bx
    prefStage(wsW, kb + 9, WB, tid);
    CMT(8,1,0,1,true,0,2, WA, sb2b, By, Bx);
    if (blk < 2) buildMaskedB(uA, Bx, 1 - ((blk + 1) & 1));
    else         buildWin(Bx, xb, rowW, lane);
    __syncthreads();
  }

  // ---- f1 (single-bf16), leaky(0.2); stages 27..33 ----
  {
    const int keep = 0;                          // unused by MODE 0/3
    char* const F1 = Wb[1];                      // odd-stage buffer
    char* const F0 = Wb[0];
    // st27 h0a [F1]: Bx->By(m0,m1)
    prefStage(wsW, 28, F0, tid);
    CMT(8,2,0,0,false,3,0, F1, f1_hb, Bx, By);
    CMT(8,2,1,1,false,3,0, F1, f1_hb, Bx, By);
    __syncthreads();
    // st28 h0b [F0]: Bx->By(m2,m3)
    prefStage(wsW, 29, F1, tid);
    CMT(8,2,0,2,false,3,0, F0, f1_hb, Bx, By);
    CMT(8,2,1,3,false,3,0, F0, f1_hb, Bx, By);
    __syncthreads();
    // st29 h1a [F1]: By->Bx(m0,m1)
    prefStage(wsW, 30, F0, tid);
    CMT(8,2,0,0,false,3,0, F1, f1_hb + 128, By, Bx);
    CMT(8,2,1,1,false,3,0, F1, f1_hb + 128, By, Bx);
    __syncthreads();
    // st30 h1b [F0]: By->Bx(m2,m3)
    prefStage(wsW, 31, F1, tid);
    CMT(8,2,0,2,false,3,0, F0, f1_hb + 128, By, Bx);
    CMT(8,2,1,3,false,3,0, F0, f1_hb + 128, By, Bx);
    __syncthreads();
    // st31 h2a [F1]: Bx->By(m0,m1)
    prefStage(wsW, 32, F0, tid);
    CMT(8,2,0,0,false,3,0, F1, f1_hb + 256, Bx, By);
    CMT(8,2,1,1,false,3,0, F1, f1_hb + 256, Bx, By);
    __syncthreads();
    // st32 h2b [F0]: Bx->By(m2,m3)
    prefStage(wsW, 33, F1, tid);
    CMT(8,2,0,2,false,3,0, F0, f1_hb + 256, Bx, By);
    CMT(8,2,1,3,false,3,0, F0, f1_hb + 256, Bx, By);
    __syncthreads();
    // st33 o [F1]: By -> resid (acc - uA), direct global store
    CMT(8,2,0,0,false,0,3, F1, f1_ob, By, Bx);
    CMT(8,2,1,1,false,0,3, F1, f1_ob, By, Bx);
  }

  // logdet: each row's sum split across lane pair (col, col+32);
  // 64-lane butterfly sums all 64 rows of this wave exactly once.
  const int tau0 = rowW + col, tau1 = rowW + 32 + col;
  float s = (tau0 < TLr ? ldet[0] : 0.f) + (tau1 < TLr ? ldet[1] : 0.f);
  #pragma unroll
  for (int off = 1; off < 64; off <<= 1) s += __shfl_xor(s, off);
  if (lane == 0) wsPart[blockIdx.x * 4 + w] = s;
}

// Deterministic final reduce: 4 wgs x 4 waves per batch element.
__global__ void pnl_ldet(const float* __restrict__ ws, float* __restrict__ outLd){
  const int b = threadIdx.x;
  float s = 0.f;
  #pragma unroll
  for (int t = 0; t < 16; ++t) s += ws[b * 16 + t];
  outLd[b] = s;
}

extern "C" void kernel_launch(void* const* d_in, const int* in_sizes, int n_in,
                              void* d_out, int out_size, void* d_ws, size_t ws_size,
                              hipStream_t stream){
  const float* x     = (const float*)d_in[0];
  const float* f1_hW = (const float*)d_in[1];
  const float* f1_hb = (const float*)d_in[2];
  const float* f1_oW = (const float*)d_in[3];
  const float* f1_ob = (const float*)d_in[4];
  const float* sW0   = (const float*)d_in[5];
  const float* sb0   = (const float*)d_in[6];
  const float* sW1   = (const float*)d_in[7];
  const float* sb1   = (const float*)d_in[8];
  const float* sW2   = (const float*)d_in[9];
  const float* sb2   = (const float*)d_in[10];
  const float* tW0   = (const float*)d_in[11];
  const float* tb0   = (const float*)d_in[12];
  const float* tW1   = (const float*)d_in[13];
  const float* tb1   = (const float*)d_in[14];
  const float* tW2   = (const float*)d_in[15];
  const float* tb2   = (const float*)d_in[16];

  char*  wsW    = (char*)d_ws;
  float* wsPart = (float*)(wsW + WSW_BYTES);          // 1024*4 floats
  float* resid  = (float*)d_out;
  float* outLd  = resid + (long)256 * TLr * 64;

  pnl_conv<<<dim3(124), dim3(256), 0, stream>>>(sW0, sW1, sW2, tW0, tW1, tW2,
                                                f1_hW, f1_oW, wsW);
  pnl_main<<<dim3(1024), dim3(256), 0, stream>>>(
      x, f1_hb, f1_ob, sb0, sb1, sb2, tb0, tb1, tb2, wsW, resid, wsPart);
  pnl_ldet<<<dim3(1), dim3(256), 0, stream>>>(wsPart, outLd);
}